// Round 1
// baseline (1276.960 us; speedup 1.0000x reference)
//
#include <hip/hip_runtime.h>

typedef unsigned long long u64;
typedef unsigned char u8;

#define VOX 0.4f
#define GAM 1.1f

// IEEE f32, no contraction: replicate numpy/jax op-for-op.
__device__ __forceinline__ float dist2d(float ax, float ay, float bx, float by) {
  float dx = __fsub_rn(ax, bx);
  float dy = __fsub_rn(ay, by);
  return __fsqrt_rn(__fadd_rn(__fmul_rn(dx, dx), __fmul_rn(dy, dy)));
}

// metric radius = norm(dims*0.5) * GAMMA
__device__ __forceinline__ float box_radius(const float* __restrict__ boxes, int m) {
  float hx = __fmul_rn(boxes[m * 7 + 3], 0.5f);
  float hy = __fmul_rn(boxes[m * 7 + 4], 0.5f);
  float nr = __fsqrt_rn(__fadd_rn(__fmul_rn(hx, hx), __fmul_rn(hy, hy)));
  return __fmul_rn(nr, GAM);
}

// ---------------- vmask: any box within (voxel-space) radius, strict < ----------
__global__ void k_vmask(const float* __restrict__ pts, const float* __restrict__ boxes,
                        const float* __restrict__ pc_start,
                        u64* __restrict__ vbits, u8* __restrict__ present,
                        int N, int M) {
  __shared__ float sqx[256], sqy[256], sr[256];
  const int tid = threadIdx.x;
  const int n = blockIdx.x * 256 + tid;
  const float psx = pc_start[0], psy = pc_start[1];
  float pvx = 0.f, pvy = 0.f;
  const bool valid = (n < N);
  if (valid) {
    pvx = __fdiv_rn(__fsub_rn(pts[n * 5 + 0], psx), VOX);
    pvy = __fdiv_rn(__fsub_rn(pts[n * 5 + 1], psy), VOX);
    present[n] = 0;
  }
  bool flag = false;
  for (int t0 = 0; t0 < M; t0 += 256) {
    const int mt = t0 + tid;
    if (mt < M) {
      sqx[tid] = __fdiv_rn(__fsub_rn(boxes[mt * 7 + 0], psx), VOX);
      sqy[tid] = __fdiv_rn(__fsub_rn(boxes[mt * 7 + 1], psy), VOX);
      float hx = __fmul_rn(boxes[mt * 7 + 3], 0.5f);
      float hy = __fmul_rn(boxes[mt * 7 + 4], 0.5f);
      float nr = __fsqrt_rn(__fadd_rn(__fmul_rn(hx, hx), __fmul_rn(hy, hy)));
      sr[tid] = __fdiv_rn(__fmul_rn(nr, GAM), VOX);  // (norm*GAMMA)/VOXEL
    }
    __syncthreads();
    const int lim = (M - t0 < 256) ? (M - t0) : 256;
    if (valid && !flag) {
      for (int j = 0; j < lim; ++j) {
        float d = dist2d(sqx[j], sqy[j], pvx, pvy);
        if (d < sr[j]) { flag = true; break; }   // strict <
      }
    }
    __syncthreads();
  }
  u64 b = __ballot(flag);
  if ((tid & 63) == 0) vbits[n >> 6] = b;   // vbits padded to grid coverage
}

// ------------- per-box ordered first-S selection (1 wave per box) ---------------
__global__ void k_select(const float* __restrict__ pts, const float* __restrict__ boxes,
                         const u64* __restrict__ vbits,
                         int* __restrict__ sidx, int* __restrict__ kcount,
                         u8* __restrict__ present, int N, int S) {
  const int m = blockIdx.x;
  const int lane = threadIdx.x;  // 64 threads
  const float bx = boxes[m * 7 + 0], by = boxes[m * 7 + 1];
  const float r = box_radius(boxes, m);
  const u64 ltmask = (1ULL << lane) - 1ULL;
  const int nwords = (N + 63) >> 6;

  int cnt = 0;
  // ones pass: first S matches in ascending index order
  for (int wi = 0; wi < nwords && cnt < S; ++wi) {
    u64 w = vbits[wi];
    if (!w) continue;
    bool flag = false;
    int n = (wi << 6) + lane;
    if ((w >> lane) & 1ULL) {
      float d = dist2d(bx, by, pts[n * 5 + 0], pts[n * 5 + 1]);
      flag = (d <= r);   // <= (metric space)
    }
    u64 b = __ballot(flag);
    if (flag) {
      int pos = cnt + __popcll(b & ltmask);
      if (pos < S) { sidx[m * S + pos] = n; present[n] = 1; }
    }
    cnt += __popcll(b);
  }
  int kOnes = cnt < S ? cnt : S;
  if (lane == 0) kcount[m] = kOnes;

  // zero-fill pass: lowest-index non-matches (top_k tie-break among zeros)
  if (kOnes < S) {
    int fill = kOnes;
    for (int wi = 0; wi < nwords && fill < S; ++wi) {
      u64 w = vbits[wi];
      int n = (wi << 6) + lane;
      bool one = false;
      if (n < N && ((w >> lane) & 1ULL)) {
        float d = dist2d(bx, by, pts[n * 5 + 0], pts[n * 5 + 1]);
        one = (d <= r);
      }
      bool z = (n < N) && !one;
      u64 b = __ballot(z);
      if (z) {
        int pos = fill + __popcll(b & ltmask);
        if (pos < S) { sidx[m * S + pos] = n; present[n] = 1; }
      }
      fill += __popcll(b);
    }
  }
}

// ------------------------- presence scan (rank = inverse) ----------------------
__global__ void k_bsum(const u8* __restrict__ present, int* __restrict__ bsum, int N) {
  const int n = blockIdx.x * 256 + threadIdx.x;
  bool f = (n < N) && present[n];
  u64 b = __ballot(f);
  __shared__ int ws[4];
  if ((threadIdx.x & 63) == 0) ws[threadIdx.x >> 6] = __popcll(b);
  __syncthreads();
  if (threadIdx.x == 0) bsum[blockIdx.x] = ws[0] + ws[1] + ws[2] + ws[3];
}

__global__ void __launch_bounds__(1024) k_scan(const int* __restrict__ bsum,
                                               int* __restrict__ boff, int nb) {
  __shared__ int s[1024];
  const int t = threadIdx.x;
  int v = (t < nb) ? bsum[t] : 0;
  s[t] = v;
  __syncthreads();
  for (int d = 1; d < 1024; d <<= 1) {
    int x = (t >= d) ? s[t - d] : 0;
    __syncthreads();
    s[t] += x;
    __syncthreads();
  }
  boff[t] = s[t] - v;                 // exclusive
  if (t == nb - 1) boff[1024] = s[t]; // U = total unique count
}

__global__ void k_rank(const u8* __restrict__ present, const int* __restrict__ boff,
                       const float* __restrict__ pts, int* __restrict__ rank_arr,
                       float* __restrict__ out_query, int N) {
  const int t = threadIdx.x;
  const int n = blockIdx.x * 256 + t;
  bool f = (n < N) && present[n];
  u64 b = __ballot(f);
  __shared__ int ws[4];
  const int wv = t >> 6, lane = t & 63;
  if (lane == 0) ws[wv] = __popcll(b);
  __syncthreads();
  int base = boff[blockIdx.x];
  for (int w = 0; w < wv; ++w) base += ws[w];
  if (f) {
    int rank = base + __popcll(b & ((1ULL << lane) - 1ULL));
    rank_arr[n] = rank;
    float* q = out_query + (size_t)rank * 5;
    const float* p = pts + (size_t)n * 5;
    q[0] = p[0]; q[1] = p[1]; q[2] = p[2]; q[3] = p[3]; q[4] = p[4];
  }
}

// ---------------- pad query rows >= U with points[0] (fill_value=0) -------------
__global__ void k_pad(const int* __restrict__ uptr, const float* __restrict__ pts,
                      float* __restrict__ out_query, int MS) {
  const int r = blockIdx.x * 256 + threadIdx.x;
  const int U = *uptr;
  if (r < MS && r >= U) {
    float* q = out_query + (size_t)r * 5;
    q[0] = pts[0]; q[1] = pts[1]; q[2] = pts[2]; q[3] = pts[3]; q[4] = pts[4];
  }
}

// ---------------------- gather outputs 0 (sampled) and 1 (idx) ------------------
__global__ void k_out(const float* __restrict__ pts, const int* __restrict__ sidx,
                      const int* __restrict__ kcount, const int* __restrict__ rank_arr,
                      float* __restrict__ out_samp, float* __restrict__ out_idx,
                      int MS, int S) {
  const int e = blockIdx.x * 256 + threadIdx.x;
  if (e >= MS) return;
  const int m = e / S;
  const int s = e - m * S;
  float* o = out_samp + (size_t)e * 5;
  if (s < kcount[m]) {
    int n = sidx[e];
    const float* p = pts + (size_t)n * 5;
    o[0] = p[0]; o[1] = p[1]; o[2] = p[2]; o[3] = p[3]; o[4] = p[4];
    out_idx[e] = (float)rank_arr[n];   // idx section read back as f32; exact <= 32767
  } else {
    o[0] = 0.f; o[1] = 0.f; o[2] = 0.f; o[3] = 0.f; o[4] = 0.f;
    out_idx[e] = 0.f;
  }
}

extern "C" void kernel_launch(void* const* d_in, const int* in_sizes, int n_in,
                              void* d_out, int out_size, void* d_ws, size_t ws_size,
                              hipStream_t stream) {
  const float* pts = (const float*)d_in[0];
  const float* boxes = (const float*)d_in[1];
  const float* pc_start = (const float*)d_in[2];
  const int N = in_sizes[0] / 5;
  const int M = in_sizes[1] / 7;
  const int S = out_size / (M * 11);   // out = M*S*5 + M*S + M*S*5
  const int MS = M * S;

  float* out_samp = (float*)d_out;
  float* out_idx = out_samp + (size_t)MS * 5;
  float* out_query = out_idx + (size_t)MS;

  const int nb = (N + 255) / 256;        // 782 for N=200000 (fits single-block scan)

  // workspace layout (16B-aligned slices)
  char* w = (char*)d_ws;
  auto take = [&](size_t bytes) {
    char* p = w;
    w += (bytes + 15) & ~(size_t)15;
    return (void*)p;
  };
  u64* vbits     = (u64*)take((size_t)(nb * 256 / 64) * 8);
  int* sidx      = (int*)take((size_t)MS * 4);
  int* kcount    = (int*)take((size_t)M * 4);
  int* rank_arr  = (int*)take((size_t)N * 4);
  int* bsum      = (int*)take((size_t)1024 * 4);
  int* boff      = (int*)take((size_t)1025 * 4);
  u8*  present   = (u8*)take((size_t)N);

  k_vmask<<<nb, 256, 0, stream>>>(pts, boxes, pc_start, vbits, present, N, M);
  k_select<<<M, 64, 0, stream>>>(pts, boxes, vbits, sidx, kcount, present, N, S);
  k_bsum<<<nb, 256, 0, stream>>>(present, bsum, N);
  k_scan<<<1, 1024, 0, stream>>>(bsum, boff, nb);
  k_rank<<<nb, 256, 0, stream>>>(present, boff, pts, rank_arr, out_query, N);
  k_pad<<<(MS + 255) / 256, 256, 0, stream>>>(boff + 1024, pts, out_query, MS);
  k_out<<<(MS + 255) / 256, 256, 0, stream>>>(pts, sidx, kcount, rank_arr,
                                              out_samp, out_idx, MS, S);
}

// Round 2
// 161.034 us; speedup vs baseline: 7.9297x; 7.9297x over previous
//
#include <hip/hip_runtime.h>

typedef unsigned long long u64;
typedef unsigned char u8;

#define VOX 0.4f
#define GAM 1.1f

// IEEE f32, no contraction: replicate numpy/jax op-for-op.
__device__ __forceinline__ float dist2d(float ax, float ay, float bx, float by) {
  float dx = __fsub_rn(ax, bx);
  float dy = __fsub_rn(ay, by);
  return __fsqrt_rn(__fadd_rn(__fmul_rn(dx, dx), __fmul_rn(dy, dy)));
}

// metric radius = norm(dims*0.5) * GAMMA
__device__ __forceinline__ float box_radius(const float* __restrict__ boxes, int m) {
  float hx = __fmul_rn(boxes[m * 7 + 3], 0.5f);
  float hy = __fmul_rn(boxes[m * 7 + 4], 0.5f);
  float nr = __fsqrt_rn(__fadd_rn(__fmul_rn(hx, hx), __fmul_rn(hy, hy)));
  return __fmul_rn(nr, GAM);
}

// ---- fused: vmask (voxel-space, strict <) + per-(box,chunk) metric match counts ----
// chunk == one block == 256 points.
__global__ void k_vmask_count(const float* __restrict__ pts, const float* __restrict__ boxes,
                              const float* __restrict__ pc_start,
                              u64* __restrict__ vbits, u8* __restrict__ present,
                              int* __restrict__ cnt, int N, int M, int nchunk) {
  __shared__ float sqx[256], sqy[256], sr[256];  // voxel-space box centers/radii (tile)
  __shared__ float cpx[256], cpy[256];           // compacted flagged points (metric xy)
  __shared__ int nf;
  const int tid = threadIdx.x;
  const int blk = blockIdx.x;
  const int n = blk * 256 + tid;
  const float psx = pc_start[0], psy = pc_start[1];
  const bool valid = (n < N);
  float px = 1e6f, py = 1e6f, pvx = 0.f, pvy = 0.f;
  if (valid) {
    px = pts[n * 5 + 0];
    py = pts[n * 5 + 1];
    pvx = __fdiv_rn(__fsub_rn(px, psx), VOX);
    pvy = __fdiv_rn(__fsub_rn(py, psy), VOX);
    present[n] = 0;
  }
  if (tid == 0) nf = 0;

  // pass 1: vmask = OR over boxes of (voxel dist < voxel radius), early break
  bool flag = false;
  for (int t0 = 0; t0 < M; t0 += 256) {
    const int mt = t0 + tid;
    if (mt < M) {
      sqx[tid] = __fdiv_rn(__fsub_rn(boxes[mt * 7 + 0], psx), VOX);
      sqy[tid] = __fdiv_rn(__fsub_rn(boxes[mt * 7 + 1], psy), VOX);
      float hx = __fmul_rn(boxes[mt * 7 + 3], 0.5f);
      float hy = __fmul_rn(boxes[mt * 7 + 4], 0.5f);
      float nr = __fsqrt_rn(__fadd_rn(__fmul_rn(hx, hx), __fmul_rn(hy, hy)));
      sr[tid] = __fdiv_rn(__fmul_rn(nr, GAM), VOX);
    }
    __syncthreads();
    const int lim = (M - t0 < 256) ? (M - t0) : 256;
    if (valid && !flag) {
      for (int j = 0; j < lim; ++j) {
        float d = dist2d(sqx[j], sqy[j], pvx, pvy);
        if (d < sr[j]) { flag = true; break; }  // strict <
      }
    }
    __syncthreads();
  }
  u64 b = __ballot(flag);
  if ((tid & 63) == 0) vbits[n >> 6] = b;

  // compact flagged points into LDS (order irrelevant for counting)
  if (flag) {
    int slot = atomicAdd(&nf, 1);
    cpx[slot] = px;
    cpy[slot] = py;
  }
  __syncthreads();
  const int nfl = nf;

  // pass 2: thread t owns box t (tiled): count metric matches in this chunk
  for (int t0 = 0; t0 < M; t0 += 256) {
    const int bm = t0 + tid;
    if (bm < M) {
      const float bx = boxes[bm * 7 + 0], by = boxes[bm * 7 + 1];
      const float r = box_radius(boxes, bm);
      int c = 0;
      for (int j = 0; j < nfl; ++j) {
        float d = dist2d(bx, by, cpx[j], cpy[j]);
        c += (d <= r) ? 1 : 0;  // metric space, <=
      }
      cnt[bm * nchunk + blk] = c;
    }
  }
}

// ---- per-box exclusive scan over chunk counts; kcount = min(total, S) ----
__global__ void __launch_bounds__(1024) k_scanbox(const int* __restrict__ cnt,
                                                  int* __restrict__ off,
                                                  int* __restrict__ kcount,
                                                  int nchunk, int S) {
  __shared__ int s[1024];
  const int m = blockIdx.x, t = threadIdx.x;
  int v = (t < nchunk) ? cnt[m * nchunk + t] : 0;
  s[t] = v;
  __syncthreads();
  for (int d = 1; d < 1024; d <<= 1) {
    int x = (t >= d) ? s[t - d] : 0;
    __syncthreads();
    s[t] += x;
    __syncthreads();
  }
  if (t < nchunk) off[m * nchunk + t] = s[t] - v;  // exclusive
  if (t == 1023) kcount[m] = (s[t] < S) ? s[t] : S;
}

// ---- scatter first-S matches per box, ordered, fully parallel over chunks ----
__global__ void k_fill(const float* __restrict__ pts, const float* __restrict__ boxes,
                       const u64* __restrict__ vbits, const int* __restrict__ cnt,
                       const int* __restrict__ off, int* __restrict__ sidx,
                       u8* __restrict__ present, int N, int S, int nchunk) {
  const int c = blockIdx.x;  // chunk
  const int m = blockIdx.y;  // box
  const int o = off[m * nchunk + c];
  if (o >= S) return;
  if (cnt[m * nchunk + c] == 0) return;
  const int lane = threadIdx.x;  // 64
  const float bx = boxes[m * 7 + 0], by = boxes[m * 7 + 1];
  const float r = box_radius(boxes, m);
  const u64 ltmask = (1ULL << lane) - 1ULL;
  int cum = o;
  for (int w = 0; w < 4; ++w) {
    const int wi = c * 4 + w;
    const u64 word = vbits[wi];
    const int n = (wi << 6) + lane;
    bool f = false;
    if ((word >> lane) & 1ULL) {
      float d = dist2d(bx, by, pts[n * 5 + 0], pts[n * 5 + 1]);
      f = (d <= r);
    }
    u64 bb = __ballot(f);
    if (f) {
      int pos = cum + __popcll(bb & ltmask);
      if (pos < S) { sidx[m * S + pos] = n; present[n] = 1; }
    }
    cum += __popcll(bb);
    if (cum >= S) break;
  }
}

// ---- zero-fill: lowest-index non-matches (top_k tie-break among zeros) ----
__global__ void k_zfill(const float* __restrict__ pts, const float* __restrict__ boxes,
                        const u64* __restrict__ vbits, const int* __restrict__ kcount,
                        int* __restrict__ sidx, u8* __restrict__ present, int N, int S) {
  const int m = blockIdx.x;
  const int k0 = kcount[m];
  if (k0 >= S) return;
  const int lane = threadIdx.x;  // 64
  const float bx = boxes[m * 7 + 0], by = boxes[m * 7 + 1];
  const float r = box_radius(boxes, m);
  const u64 ltmask = (1ULL << lane) - 1ULL;
  const int nwords = (N + 63) >> 6;
  int fill = k0;
  for (int wi = 0; wi < nwords && fill < S; ++wi) {
    const u64 w = vbits[wi];
    const int n = (wi << 6) + lane;
    bool one = false;
    if (n < N && ((w >> lane) & 1ULL)) {
      float d = dist2d(bx, by, pts[n * 5 + 0], pts[n * 5 + 1]);
      one = (d <= r);
    }
    const bool z = (n < N) && !one;
    u64 b = __ballot(z);
    if (z) {
      int pos = fill + __popcll(b & ltmask);
      if (pos < S) { sidx[m * S + pos] = n; present[n] = 1; }
    }
    fill += __popcll(b);
  }
}

// ------------------------- presence scan (rank = inverse) ----------------------
__global__ void k_bsum(const u8* __restrict__ present, int* __restrict__ bsum, int N) {
  const int n = blockIdx.x * 256 + threadIdx.x;
  bool f = (n < N) && present[n];
  u64 b = __ballot(f);
  __shared__ int ws[4];
  if ((threadIdx.x & 63) == 0) ws[threadIdx.x >> 6] = __popcll(b);
  __syncthreads();
  if (threadIdx.x == 0) bsum[blockIdx.x] = ws[0] + ws[1] + ws[2] + ws[3];
}

__global__ void __launch_bounds__(1024) k_scan(const int* __restrict__ bsum,
                                               int* __restrict__ boff, int nb) {
  __shared__ int s[1024];
  const int t = threadIdx.x;
  int v = (t < nb) ? bsum[t] : 0;
  s[t] = v;
  __syncthreads();
  for (int d = 1; d < 1024; d <<= 1) {
    int x = (t >= d) ? s[t - d] : 0;
    __syncthreads();
    s[t] += x;
    __syncthreads();
  }
  boff[t] = s[t] - v;                 // exclusive
  if (t == nb - 1) boff[1024] = s[t]; // U = total unique count
}

__global__ void k_rank(const u8* __restrict__ present, const int* __restrict__ boff,
                       const float* __restrict__ pts, int* __restrict__ rank_arr,
                       float* __restrict__ out_query, int N) {
  const int t = threadIdx.x;
  const int n = blockIdx.x * 256 + t;
  bool f = (n < N) && present[n];
  u64 b = __ballot(f);
  __shared__ int ws[4];
  const int wv = t >> 6, lane = t & 63;
  if (lane == 0) ws[wv] = __popcll(b);
  __syncthreads();
  int base = boff[blockIdx.x];
  for (int w = 0; w < wv; ++w) base += ws[w];
  if (f) {
    int rank = base + __popcll(b & ((1ULL << lane) - 1ULL));
    rank_arr[n] = rank;
    float* q = out_query + (size_t)rank * 5;
    const float* p = pts + (size_t)n * 5;
    q[0] = p[0]; q[1] = p[1]; q[2] = p[2]; q[3] = p[3]; q[4] = p[4];
  }
}

// ---------------- pad query rows >= U with points[0] (fill_value=0) -------------
__global__ void k_pad(const int* __restrict__ uptr, const float* __restrict__ pts,
                      float* __restrict__ out_query, int MS) {
  const int r = blockIdx.x * 256 + threadIdx.x;
  const int U = *uptr;
  if (r < MS && r >= U) {
    float* q = out_query + (size_t)r * 5;
    q[0] = pts[0]; q[1] = pts[1]; q[2] = pts[2]; q[3] = pts[3]; q[4] = pts[4];
  }
}

// ---------------------- gather outputs 0 (sampled) and 1 (idx) ------------------
__global__ void k_out(const float* __restrict__ pts, const int* __restrict__ sidx,
                      const int* __restrict__ kcount, const int* __restrict__ rank_arr,
                      float* __restrict__ out_samp, float* __restrict__ out_idx,
                      int MS, int S) {
  const int e = blockIdx.x * 256 + threadIdx.x;
  if (e >= MS) return;
  const int m = e / S;
  const int s = e - m * S;
  float* o = out_samp + (size_t)e * 5;
  if (s < kcount[m]) {
    int n = sidx[e];
    const float* p = pts + (size_t)n * 5;
    o[0] = p[0]; o[1] = p[1]; o[2] = p[2]; o[3] = p[3]; o[4] = p[4];
    out_idx[e] = (float)rank_arr[n];   // idx section read back as f32; exact
  } else {
    o[0] = 0.f; o[1] = 0.f; o[2] = 0.f; o[3] = 0.f; o[4] = 0.f;
    out_idx[e] = 0.f;
  }
}

extern "C" void kernel_launch(void* const* d_in, const int* in_sizes, int n_in,
                              void* d_out, int out_size, void* d_ws, size_t ws_size,
                              hipStream_t stream) {
  const float* pts = (const float*)d_in[0];
  const float* boxes = (const float*)d_in[1];
  const float* pc_start = (const float*)d_in[2];
  const int N = in_sizes[0] / 5;
  const int M = in_sizes[1] / 7;
  const int S = out_size / (M * 11);   // out = M*S*5 + M*S + M*S*5
  const int MS = M * S;

  float* out_samp = (float*)d_out;
  float* out_idx = out_samp + (size_t)MS * 5;
  float* out_query = out_idx + (size_t)MS;

  const int nb = (N + 255) / 256;   // = nchunk; 782 for N=200000 (<=1024 for k_scanbox)
  const int nchunk = nb;

  // workspace layout (16B-aligned slices)
  char* w = (char*)d_ws;
  auto take = [&](size_t bytes) {
    char* p = w;
    w += (bytes + 15) & ~(size_t)15;
    return (void*)p;
  };
  u64* vbits     = (u64*)take((size_t)(nb * 4) * 8);
  int* cnt       = (int*)take((size_t)M * nchunk * 4);
  int* off       = (int*)take((size_t)M * nchunk * 4);
  int* sidx      = (int*)take((size_t)MS * 4);
  int* kcount    = (int*)take((size_t)M * 4);
  int* rank_arr  = (int*)take((size_t)N * 4);
  int* bsum      = (int*)take((size_t)1024 * 4);
  int* boff      = (int*)take((size_t)1025 * 4);
  u8*  present   = (u8*)take((size_t)N);

  k_vmask_count<<<nb, 256, 0, stream>>>(pts, boxes, pc_start, vbits, present, cnt, N, M, nchunk);
  k_scanbox<<<M, 1024, 0, stream>>>(cnt, off, kcount, nchunk, S);
  k_fill<<<dim3(nchunk, M), 64, 0, stream>>>(pts, boxes, vbits, cnt, off, sidx, present, N, S, nchunk);
  k_zfill<<<M, 64, 0, stream>>>(pts, boxes, vbits, kcount, sidx, present, N, S);
  k_bsum<<<nb, 256, 0, stream>>>(present, bsum, N);
  k_scan<<<1, 1024, 0, stream>>>(bsum, boff, nb);
  k_rank<<<nb, 256, 0, stream>>>(present, boff, pts, rank_arr, out_query, N);
  k_pad<<<(MS + 255) / 256, 256, 0, stream>>>(boff + 1024, pts, out_query, MS);
  k_out<<<(MS + 255) / 256, 256, 0, stream>>>(pts, sidx, kcount, rank_arr,
                                              out_samp, out_idx, MS, S);
}

// Round 3
// 129.159 us; speedup vs baseline: 9.8867x; 1.2468x over previous
//
#include <hip/hip_runtime.h>

typedef unsigned long long u64;
typedef unsigned char u8;

#define VOX 0.4f
#define GAM 1.1f

// IEEE f32, no contraction: replicate numpy/jax op-for-op.
__device__ __forceinline__ float dist2d(float ax, float ay, float bx, float by) {
  float dx = __fsub_rn(ax, bx);
  float dy = __fsub_rn(ay, by);
  return __fsqrt_rn(__fadd_rn(__fmul_rn(dx, dx), __fmul_rn(dy, dy)));
}

// metric radius = norm(dims*0.5) * GAMMA
__device__ __forceinline__ float box_radius(const float* __restrict__ boxes, int m) {
  float hx = __fmul_rn(boxes[m * 7 + 3], 0.5f);
  float hy = __fmul_rn(boxes[m * 7 + 4], 0.5f);
  float nr = __fsqrt_rn(__fadd_rn(__fmul_rn(hx, hx), __fmul_rn(hy, hy)));
  return __fmul_rn(nr, GAM);
}

// ---- fused: vmask (voxel-space, strict <) + ORDERED compaction + per-(chunk,box)
//      metric match counts. chunk == one block == 256 points. cnt layout: [c][M].
__global__ void k_vmask_count(const float* __restrict__ pts, const float* __restrict__ boxes,
                              const float* __restrict__ pc_start,
                              u64* __restrict__ vbits, u8* __restrict__ present,
                              int* __restrict__ cnt,
                              float* __restrict__ cpxg, float* __restrict__ cpyg,
                              int* __restrict__ cpng, int* __restrict__ nflags,
                              int N, int M) {
  __shared__ float sqx[256], sqy[256], sr[256];  // voxel-space box centers/radii (tile)
  __shared__ float cpx[256], cpy[256];           // compacted flagged points (metric xy)
  __shared__ int cpn[256];                       // compacted point indices
  __shared__ int wcnt[4];
  const int tid = threadIdx.x;
  const int blk = blockIdx.x;
  const int n = blk * 256 + tid;
  const int wv = tid >> 6, lane = tid & 63;
  const float psx = pc_start[0], psy = pc_start[1];
  const bool valid = (n < N);
  float px = 1e6f, py = 1e6f, pvx = 0.f, pvy = 0.f;
  if (valid) {
    px = pts[n * 5 + 0];
    py = pts[n * 5 + 1];
    pvx = __fdiv_rn(__fsub_rn(px, psx), VOX);
    pvy = __fdiv_rn(__fsub_rn(py, psy), VOX);
    present[n] = 0;
  }

  // pass 1: vmask = OR over boxes of (voxel dist < voxel radius), early break
  bool flag = false;
  for (int t0 = 0; t0 < M; t0 += 256) {
    const int mt = t0 + tid;
    if (mt < M) {
      sqx[tid] = __fdiv_rn(__fsub_rn(boxes[mt * 7 + 0], psx), VOX);
      sqy[tid] = __fdiv_rn(__fsub_rn(boxes[mt * 7 + 1], psy), VOX);
      float hx = __fmul_rn(boxes[mt * 7 + 3], 0.5f);
      float hy = __fmul_rn(boxes[mt * 7 + 4], 0.5f);
      float nr = __fsqrt_rn(__fadd_rn(__fmul_rn(hx, hx), __fmul_rn(hy, hy)));
      sr[tid] = __fdiv_rn(__fmul_rn(nr, GAM), VOX);
    }
    __syncthreads();
    const int lim = (M - t0 < 256) ? (M - t0) : 256;
    if (valid && !flag) {
      for (int j = 0; j < lim; ++j) {
        float d = dist2d(sqx[j], sqy[j], pvx, pvy);
        if (d < sr[j]) { flag = true; break; }  // strict <
      }
    }
    __syncthreads();
  }
  u64 b = __ballot(flag);
  if (lane == 0) {
    vbits[n >> 6] = b;
    wcnt[wv] = __popcll(b);
  }
  __syncthreads();

  // ORDERED compaction (ascending n) of flagged points into LDS, then global
  int base = 0;
  for (int w = 0; w < wv; ++w) base += wcnt[w];
  if (flag) {
    int slot = base + __popcll(b & ((1ULL << lane) - 1ULL));
    cpx[slot] = px;
    cpy[slot] = py;
    cpn[slot] = n;
  }
  __syncthreads();
  const int nfl = wcnt[0] + wcnt[1] + wcnt[2] + wcnt[3];
  if (tid == 0) nflags[blk] = nfl;
  if (tid < nfl) {
    cpxg[blk * 256 + tid] = cpx[tid];
    cpyg[blk * 256 + tid] = cpy[tid];
    cpng[blk * 256 + tid] = cpn[tid];
  }

  // pass 2: thread t owns box t (tiled): count metric matches in this chunk
  for (int t0 = 0; t0 < M; t0 += 256) {
    const int bm = t0 + tid;
    if (bm < M) {
      const float bx = boxes[bm * 7 + 0], by = boxes[bm * 7 + 1];
      const float r = box_radius(boxes, bm);
      int c = 0;
      for (int j = 0; j < nfl; ++j) {
        float d = dist2d(bx, by, cpx[j], cpy[j]);
        c += (d <= r) ? 1 : 0;  // metric space, <=
      }
      cnt[blk * M + bm] = c;  // chunk-major, coalesced
    }
  }
}

// ---- per-box exclusive scan over chunk counts (strided reads, L2-resident) ----
__global__ void __launch_bounds__(1024) k_scanbox(const int* __restrict__ cnt,
                                                  int* __restrict__ off,
                                                  int* __restrict__ kcount,
                                                  int nchunk, int M, int S) {
  __shared__ int s[1024];
  const int m = blockIdx.x, t = threadIdx.x;
  int v = (t < nchunk) ? cnt[t * M + m] : 0;
  s[t] = v;
  __syncthreads();
  for (int d = 1; d < 1024; d <<= 1) {
    int x = (t >= d) ? s[t - d] : 0;
    __syncthreads();
    s[t] += x;
    __syncthreads();
  }
  if (t < nchunk) off[t * M + m] = s[t] - v;  // exclusive, chunk-major
  if (t == 1023) kcount[m] = (s[t] < S) ? s[t] : S;
}

// ---- scatter first-S matches: chunk-major blocks, thread = box, LDS-staged pts ----
__global__ void k_fill(const float* __restrict__ boxes,
                       const float* __restrict__ cpxg, const float* __restrict__ cpyg,
                       const int* __restrict__ cpng, const int* __restrict__ nflags,
                       const int* __restrict__ off, int* __restrict__ sidx,
                       u8* __restrict__ present, int M, int S) {
  const int c = blockIdx.x;
  const int tid = threadIdx.x;
  const int nf = nflags[c];
  if (nf == 0) return;
  __shared__ float sx[256], sy[256];
  __shared__ int sn[256];
  if (tid < nf) {
    sx[tid] = cpxg[c * 256 + tid];
    sy[tid] = cpyg[c * 256 + tid];
    sn[tid] = cpng[c * 256 + tid];
  }
  __syncthreads();
  for (int m = tid; m < M; m += 256) {
    int cum = off[c * M + m];
    if (cum >= S) continue;
    const float bx = boxes[m * 7 + 0], by = boxes[m * 7 + 1];
    const float r = box_radius(boxes, m);
    for (int j = 0; j < nf; ++j) {
      float d = dist2d(bx, by, sx[j], sy[j]);
      if (d <= r) {
        int pn = sn[j];
        sidx[m * S + cum] = pn;
        present[pn] = 1;
        if (++cum >= S) break;
      }
    }
  }
}

// ---- zero-fill: lowest-index non-matches (top_k tie-break among zeros) ----
__global__ void k_zfill(const float* __restrict__ pts, const float* __restrict__ boxes,
                        const u64* __restrict__ vbits, const int* __restrict__ kcount,
                        int* __restrict__ sidx, u8* __restrict__ present, int N, int S) {
  const int m = blockIdx.x;
  const int k0 = kcount[m];
  if (k0 >= S) return;
  const int lane = threadIdx.x;  // 64
  const float bx = boxes[m * 7 + 0], by = boxes[m * 7 + 1];
  const float r = box_radius(boxes, m);
  const u64 ltmask = (1ULL << lane) - 1ULL;
  const int nwords = (N + 63) >> 6;
  int fill = k0;
  for (int wi = 0; wi < nwords && fill < S; ++wi) {
    const u64 w = vbits[wi];
    const int n = (wi << 6) + lane;
    bool one = false;
    if (n < N && ((w >> lane) & 1ULL)) {
      float d = dist2d(bx, by, pts[n * 5 + 0], pts[n * 5 + 1]);
      one = (d <= r);
    }
    const bool z = (n < N) && !one;
    u64 b = __ballot(z);
    if (z) {
      int pos = fill + __popcll(b & ltmask);
      if (pos < S) { sidx[m * S + pos] = n; present[n] = 1; }
    }
    fill += __popcll(b);
  }
}

// ------------------------- presence scan (rank = inverse) ----------------------
__global__ void k_bsum(const u8* __restrict__ present, int* __restrict__ bsum, int N) {
  const int n = blockIdx.x * 256 + threadIdx.x;
  bool f = (n < N) && present[n];
  u64 b = __ballot(f);
  __shared__ int ws[4];
  if ((threadIdx.x & 63) == 0) ws[threadIdx.x >> 6] = __popcll(b);
  __syncthreads();
  if (threadIdx.x == 0) bsum[blockIdx.x] = ws[0] + ws[1] + ws[2] + ws[3];
}

__global__ void __launch_bounds__(1024) k_scan(const int* __restrict__ bsum,
                                               int* __restrict__ boff, int nb) {
  __shared__ int s[1024];
  const int t = threadIdx.x;
  int v = (t < nb) ? bsum[t] : 0;
  s[t] = v;
  __syncthreads();
  for (int d = 1; d < 1024; d <<= 1) {
    int x = (t >= d) ? s[t - d] : 0;
    __syncthreads();
    s[t] += x;
    __syncthreads();
  }
  boff[t] = s[t] - v;                 // exclusive
  if (t == nb - 1) boff[1024] = s[t]; // U = total unique count
}

__global__ void k_rank(const u8* __restrict__ present, const int* __restrict__ boff,
                       const float* __restrict__ pts, int* __restrict__ rank_arr,
                       float* __restrict__ out_query, int N) {
  const int t = threadIdx.x;
  const int n = blockIdx.x * 256 + t;
  bool f = (n < N) && present[n];
  u64 b = __ballot(f);
  __shared__ int ws[4];
  const int wv = t >> 6, lane = t & 63;
  if (lane == 0) ws[wv] = __popcll(b);
  __syncthreads();
  int base = boff[blockIdx.x];
  for (int w = 0; w < wv; ++w) base += ws[w];
  if (f) {
    int rank = base + __popcll(b & ((1ULL << lane) - 1ULL));
    rank_arr[n] = rank;
    float* q = out_query + (size_t)rank * 5;
    const float* p = pts + (size_t)n * 5;
    q[0] = p[0]; q[1] = p[1]; q[2] = p[2]; q[3] = p[3]; q[4] = p[4];
  }
}

// ---------------- pad query rows >= U with points[0] (fill_value=0) -------------
__global__ void k_pad(const int* __restrict__ uptr, const float* __restrict__ pts,
                      float* __restrict__ out_query, int MS) {
  const int r = blockIdx.x * 256 + threadIdx.x;
  const int U = *uptr;
  if (r < MS && r >= U) {
    float* q = out_query + (size_t)r * 5;
    q[0] = pts[0]; q[1] = pts[1]; q[2] = pts[2]; q[3] = pts[3]; q[4] = pts[4];
  }
}

// ---------------------- gather outputs 0 (sampled) and 1 (idx) ------------------
__global__ void k_out(const float* __restrict__ pts, const int* __restrict__ sidx,
                      const int* __restrict__ kcount, const int* __restrict__ rank_arr,
                      float* __restrict__ out_samp, float* __restrict__ out_idx,
                      int MS, int S) {
  const int e = blockIdx.x * 256 + threadIdx.x;
  if (e >= MS) return;
  const int m = e / S;
  const int s = e - m * S;
  float* o = out_samp + (size_t)e * 5;
  if (s < kcount[m]) {
    int n = sidx[e];
    const float* p = pts + (size_t)n * 5;
    o[0] = p[0]; o[1] = p[1]; o[2] = p[2]; o[3] = p[3]; o[4] = p[4];
    out_idx[e] = (float)rank_arr[n];   // idx section read back as f32; exact
  } else {
    o[0] = 0.f; o[1] = 0.f; o[2] = 0.f; o[3] = 0.f; o[4] = 0.f;
    out_idx[e] = 0.f;
  }
}

extern "C" void kernel_launch(void* const* d_in, const int* in_sizes, int n_in,
                              void* d_out, int out_size, void* d_ws, size_t ws_size,
                              hipStream_t stream) {
  const float* pts = (const float*)d_in[0];
  const float* boxes = (const float*)d_in[1];
  const float* pc_start = (const float*)d_in[2];
  const int N = in_sizes[0] / 5;
  const int M = in_sizes[1] / 7;
  const int S = out_size / (M * 11);   // out = M*S*5 + M*S + M*S*5
  const int MS = M * S;

  float* out_samp = (float*)d_out;
  float* out_idx = out_samp + (size_t)MS * 5;
  float* out_query = out_idx + (size_t)MS;

  const int nb = (N + 255) / 256;   // = nchunk; 782 for N=200000 (<=1024 for scans)
  const int nchunk = nb;

  // workspace layout (16B-aligned slices)
  char* w = (char*)d_ws;
  auto take = [&](size_t bytes) {
    char* p = w;
    w += (bytes + 15) & ~(size_t)15;
    return (void*)p;
  };
  u64* vbits     = (u64*)take((size_t)(nb * 4) * 8);
  int* cnt       = (int*)take((size_t)nchunk * M * 4);
  int* off       = (int*)take((size_t)nchunk * M * 4);
  float* cpxg    = (float*)take((size_t)nchunk * 256 * 4);
  float* cpyg    = (float*)take((size_t)nchunk * 256 * 4);
  int* cpng      = (int*)take((size_t)nchunk * 256 * 4);
  int* nflags    = (int*)take((size_t)nchunk * 4);
  int* sidx      = (int*)take((size_t)MS * 4);
  int* kcount    = (int*)take((size_t)M * 4);
  int* rank_arr  = (int*)take((size_t)N * 4);
  int* bsum      = (int*)take((size_t)1024 * 4);
  int* boff      = (int*)take((size_t)1025 * 4);
  u8*  present   = (u8*)take((size_t)N);

  k_vmask_count<<<nb, 256, 0, stream>>>(pts, boxes, pc_start, vbits, present, cnt,
                                        cpxg, cpyg, cpng, nflags, N, M);
  k_scanbox<<<M, 1024, 0, stream>>>(cnt, off, kcount, nchunk, M, S);
  k_fill<<<nchunk, 256, 0, stream>>>(boxes, cpxg, cpyg, cpng, nflags, off, sidx, present, M, S);
  k_zfill<<<M, 64, 0, stream>>>(pts, boxes, vbits, kcount, sidx, present, N, S);
  k_bsum<<<nb, 256, 0, stream>>>(present, bsum, N);
  k_scan<<<1, 1024, 0, stream>>>(bsum, boff, nb);
  k_rank<<<nb, 256, 0, stream>>>(present, boff, pts, rank_arr, out_query, N);
  k_pad<<<(MS + 255) / 256, 256, 0, stream>>>(boff + 1024, pts, out_query, MS);
  k_out<<<(MS + 255) / 256, 256, 0, stream>>>(pts, sidx, kcount, rank_arr,
                                              out_samp, out_idx, MS, S);
}